// Round 18
// baseline (100.841 us; speedup 1.0000x reference)
//
#include <hip/hip_runtime.h>
#include <hip/hip_bf16.h>

#define N_NODES 8192
#define N_EDGES 131072
#define LN_EPS  1e-5f

typedef __attribute__((ext_vector_type(8))) short bf16x8;
typedef __attribute__((ext_vector_type(4))) short bf16x4;
typedef __attribute__((ext_vector_type(4))) float f32x4;

// silu via v_rcp_f32: avoids IEEE div expansion (no fast-math in harness)
__device__ __forceinline__ float silu_f(float x) {
    return x * __builtin_amdgcn_rcpf(1.0f + __expf(-x));
}

// fp32 -> bf16 RNE (scalar)
__device__ __forceinline__ unsigned short f2bf(float x) {
    union { float f; unsigned int u; } v; v.f = x;
    unsigned int r = v.u + 0x7FFFu + ((v.u >> 16) & 1u);
    return (unsigned short)(r >> 16);
}
__device__ __forceinline__ float bf2f(unsigned short u) {
    union { float f; unsigned int x; } v; v.x = ((unsigned int)u) << 16;
    return v.f;
}
// fp32 pair -> packed bf16x2 via v_cvt_pk_bf16_f32
__device__ __forceinline__ unsigned int pk2(float a, float b) {
    float2 t; t.x = a; t.y = b;
    union { __hip_bfloat162 h; unsigned int u; } v;
    v.h = __float22bfloat162_rn(t);
    return v.u;
}
__device__ __forceinline__ bf16x8 pack8(float4 u, float4 v) {
    union { bf16x8 b; unsigned int w[4]; } o;
    o.w[0] = pk2(u.x, u.y); o.w[1] = pk2(u.z, u.w);
    o.w[2] = pk2(v.x, v.y); o.w[3] = pk2(v.z, v.w);
    return o.b;
}
__device__ __forceinline__ bf16x4 pack4(float a, float b, float c, float d) {
    union { bf16x4 v; unsigned int u[2]; } o;
    o.u[0] = pk2(a, b); o.u[1] = pk2(c, d);
    return o.v;
}
__device__ __forceinline__ f32x4 mfma16(bf16x8 a, bf16x8 b, f32x4 c) {
    return __builtin_amdgcn_mfma_f32_16x16x32_bf16(a, b, c, 0, 0, 0);
}
// K=16 MFMA: A/B = 4 bf16 per lane (lane l15 = row/col, k = lk*4..+3)
#if __has_builtin(__builtin_amdgcn_mfma_f32_16x16x16bf16_1k)
__device__ __forceinline__ f32x4 mfma_k16(bf16x4 a, bf16x4 b, f32x4 c) {
    return __builtin_amdgcn_mfma_f32_16x16x16bf16_1k(a, b, c, 0, 0, 0);
}
#else
__device__ __forceinline__ f32x4 mfma_k16(bf16x4 a, bf16x4 b, f32x4 c) {
    f32x4 d;
    asm("v_mfma_f32_16x16x16_bf16 %0, %1, %2, %3"
        : "=v"(d) : "v"(a), "v"(b), "v"(c));
    return d;
}
#endif

// ---------------------------------------------------------------------------
// Kernel 0: weight prep (round-14 verified, unchanged).
// ---------------------------------------------------------------------------
__global__ __launch_bounds__(256) void prep_kernel(
    const float* __restrict__ W_w, const float* __restrict__ W_t1,
    const float* __restrict__ W_t2, const float* __restrict__ Wvq,
    const float* __restrict__ Wvk0, const float* __restrict__ Wvk1,
    const float* __restrict__ Wvk2,
    unsigned short* __restrict__ Wtw, unsigned short* __restrict__ Wt1b,
    unsigned short* __restrict__ Wt2b, unsigned short* __restrict__ Wqt,
    unsigned short* __restrict__ Wk0t, unsigned short* __restrict__ Wk1t,
    unsigned short* __restrict__ Wk2t)
{
    int i = blockIdx.x * 256 + threadIdx.x;
    if (i < 16384) {
        int n = i >> 7, k = i & 127;
        Wt1b[i] = f2bf(W_t1[k * 128 + n]);
        Wt2b[i] = f2bf(W_t2[k * 128 + n]);
    }
    if (i < 4096) {
        { int n = i >> 5, k = i & 31; Wtw[i] = f2bf(W_w[k * 128 + n]); }
        int r = i >> 7, d = i & 127;
        Wqt[i]  = f2bf(Wvq [d * 32 + r]);
        Wk0t[i] = f2bf(Wvk0[d * 32 + r]);
        Wk1t[i] = f2bf(Wvk1[d * 32 + r]);
        Wk2t[i] = f2bf(Wvk2[d * 32 + r]);
    }
}

// ---------------------------------------------------------------------------
// Kernel 1: MFMA projections (round-12 verified, unchanged). [n][l][r32].
// ---------------------------------------------------------------------------
template<int S, int LOFF>
__device__ __forceinline__ void proj_body(
    const float* __restrict__ X, const unsigned short* __restrict__ Wqt,
    const unsigned short* __restrict__ Wkt,
    unsigned short* __restrict__ eq, unsigned short* __restrict__ ek,
    int row0)
{
    const int tid  = threadIdx.x;
    const int lane = tid & 63;
    const int wv   = tid >> 6;
    const int l15  = lane & 15;
    const int lk   = lane >> 4;
    const int xrow = row0 + wv * 16 + l15;

    bf16x8 xf[4];
    #pragma unroll
    for (int kt = 0; kt < 4; ++kt) {
        const float* p = X + (size_t)xrow * 128 + kt * 32 + lk * 8;
        xf[kt] = pack8(*(const float4*)p, *(const float4*)(p + 4));
    }

    f32x4 qa[2], ka[2];
    #pragma unroll
    for (int h = 0; h < 2; ++h) {
        qa[h] = (f32x4){0.f, 0.f, 0.f, 0.f};
        ka[h] = (f32x4){0.f, 0.f, 0.f, 0.f};
    }
    #pragma unroll
    for (int kt = 0; kt < 4; ++kt) {
        #pragma unroll
        for (int h = 0; h < 2; ++h) {
            bf16x8 wq = *(const bf16x8*)&Wqt[(h * 16 + l15) * 128 + kt * 32 + lk * 8];
            bf16x8 wk = *(const bf16x8*)&Wkt[(h * 16 + l15) * 128 + kt * 32 + lk * 8];
            qa[h] = mfma16(wq, xf[kt], qa[h]);
            ka[h] = mfma16(wk, xf[kt], ka[h]);
        }
    }

    const int n = xrow / S;
    const int l = xrow % S + LOFF;
    const size_t base = (size_t)n * 512 + (size_t)l * 32;   // [n][l][r32]
    #pragma unroll
    for (int h = 0; h < 2; ++h) {
        union { ushort4 s; unsigned int u[2]; } pq, pk_;
        pq.u[0]  = pk2(qa[h][0], qa[h][1]); pq.u[1]  = pk2(qa[h][2], qa[h][3]);
        pk_.u[0] = pk2(ka[h][0], ka[h][1]); pk_.u[1] = pk2(ka[h][2], ka[h][3]);
        *(ushort4*)&eq[base + h * 16 + lk * 4] = pq.s;
        *(ushort4*)&ek[base + h * 16 + lk * 4] = pk_.s;
    }
}

__global__ __launch_bounds__(256) void proj_kernel(
    const float* __restrict__ X0, const float* __restrict__ X1,
    const float* __restrict__ X2,
    const unsigned short* __restrict__ Wqt,
    const unsigned short* __restrict__ Wk0t,
    const unsigned short* __restrict__ Wk1t,
    const unsigned short* __restrict__ Wk2t,
    unsigned short* __restrict__ eq, unsigned short* __restrict__ ek)
{
    const int b = blockIdx.x;
    if (b < 384)
        proj_body<3, 0>(X0, Wqt, Wk0t, eq, ek, b * 64);
    else if (b < 1024)
        proj_body<5, 3>(X1, Wqt, Wk1t, eq, ek, (b - 384) * 64);
    else
        proj_body<7, 8>(X2, Wqt, Wk2t, eq, ek, (b - 1024) * 64);
}

// ---------------------------------------------------------------------------
// Kernel 2: wn (round-12 verified, unchanged). 2 edges/thread, [n][l][r32].
// ---------------------------------------------------------------------------
__device__ __forceinline__ float edge_w_f(
    const float* qv, const float* kv, const float* rv)
{
    float qk = 0.f;
    #pragma unroll
    for (int l = 0; l < 15; ++l) qk = fmaf(qv[l], kv[l], qk);
    float c0 = 2.f, c1 = 2.f, c2 = 2.f;
    #pragma unroll
    for (int l = 0; l < 3; ++l)  c0 -= rv[l] * rv[l];
    #pragma unroll
    for (int l = 3; l < 8; ++l)  c1 -= rv[l] * rv[l];
    #pragma unroll
    for (int l = 8; l < 15; ++l) c2 -= rv[l] * rv[l];
    float dq0 = 0.f, dk0 = 0.f, dq1 = 0.f, dk1 = 0.f, dq2 = 0.f, dk2 = 0.f;
    #pragma unroll
    for (int l = 0; l < 3; ++l)  { dq0 = fmaf(qv[l], rv[l], dq0); dk0 = fmaf(kv[l], rv[l], dk0); }
    #pragma unroll
    for (int l = 3; l < 8; ++l)  { dq1 = fmaf(qv[l], rv[l], dq1); dk1 = fmaf(kv[l], rv[l], dk1); }
    #pragma unroll
    for (int l = 8; l < 15; ++l) { dq2 = fmaf(qv[l], rv[l], dq2); dk2 = fmaf(kv[l], rv[l], dk2); }
    return qk - dq0 * dk0 * c0 - dq1 * dk1 * c1 - dq2 * dk2 * c2;
}

__global__ __launch_bounds__(256) void wn_kernel(
    const unsigned short* __restrict__ eq, const unsigned short* __restrict__ ek,
    const float* __restrict__ r0, const float* __restrict__ r1,
    const float* __restrict__ r2, const int* __restrict__ eidx,
    const float* __restrict__ ln_g, const float* __restrict__ ln_b,
    unsigned short* __restrict__ wn)
{
    const int tid = threadIdx.x;
    const int r   = tid & 31;
    const int hw  = tid >> 5;
    const int e0  = blockIdx.x * 16 + hw * 2;
    const int e1  = e0 + 1;
    const float g  = ln_g[r];
    const float bb = ln_b[r];

    const int nj0 = eidx[e0], ni0 = eidx[N_EDGES + e0];
    const int nj1 = eidx[e1], ni1 = eidx[N_EDGES + e1];

    const unsigned short* qp0 = eq + (size_t)ni0 * 512 + r;
    const unsigned short* kp0 = ek + (size_t)nj0 * 512 + r;
    const unsigned short* qp1 = eq + (size_t)ni1 * 512 + r;
    const unsigned short* kp1 = ek + (size_t)nj1 * 512 + r;

    float qv0[15], kv0[15], qv1[15], kv1[15];
    #pragma unroll
    for (int l = 0; l < 15; ++l) {
        qv0[l] = bf2f(qp0[l * 32]);
        kv0[l] = bf2f(kp0[l * 32]);
        qv1[l] = bf2f(qp1[l * 32]);
        kv1[l] = bf2f(kp1[l * 32]);
    }

    float rva[15], rvb[15];
    #pragma unroll
    for (int c = 0; c < 3; ++c) { rva[c]     = r0[e0 * 3 + c]; rvb[c]     = r0[e1 * 3 + c]; }
    #pragma unroll
    for (int c = 0; c < 5; ++c) { rva[3 + c] = r1[e0 * 5 + c]; rvb[3 + c] = r1[e1 * 5 + c]; }
    #pragma unroll
    for (int c = 0; c < 7; ++c) { rva[8 + c] = r2[e0 * 7 + c]; rvb[8 + c] = r2[e1 * 7 + c]; }

    const float w0 = edge_w_f(qv0, kv0, rva);
    const float w1 = edge_w_f(qv1, kv1, rvb);

    float s0 = w0, s20 = w0 * w0, s1 = w1, s21 = w1 * w1;
    #pragma unroll
    for (int off = 1; off < 32; off <<= 1) {
        s0  += __shfl_xor(s0,  off); s20 += __shfl_xor(s20, off);
        s1  += __shfl_xor(s1,  off); s21 += __shfl_xor(s21, off);
    }
    const float mu0   = s0 * (1.f / 32.f);
    const float var0  = s20 * (1.f / 32.f) - mu0 * mu0;
    const float mu1   = s1 * (1.f / 32.f);
    const float var1  = s21 * (1.f / 32.f) - mu1 * mu1;
    wn[(size_t)e0 * 32 + r] = f2bf((w0 - mu0) * rsqrtf(var0 + LN_EPS) * g + bb);
    wn[(size_t)e1 * 32 + r] = f2bf((w1 - mu1) * rsqrtf(var1 + LN_EPS) * g + bb);
}

// ---------------------------------------------------------------------------
// Kernel 3: round-14 structure (best: 42us) + SWAPPED GEMM2/dw operands.
// mfma_k16(A=W2-frag, B=h) / mfma16(A=Ww-frag, B=wn) -> D[n][edge]: lane
// l15 = edge, j = 4 CONSECUTIVE n -> epilogue is 16 coalesced float4 stores
// per wave (vs 64 scalar stride-512B stores). Operand loads unchanged.
// 512 threads = 8 waves x 32 edges = 256 edges/block, grid 512.
// LDS 72KB -> 2 blocks/CU -> 16 waves/CU (4/SIMD). One barrier.
// ---------------------------------------------------------------------------
__global__ __launch_bounds__(512, 4) void edge_kernel(
    const float* __restrict__ t_ij,
    const unsigned short* __restrict__ wn,
    const unsigned short* __restrict__ Wtw, const float* __restrict__ b_w,
    const unsigned short* __restrict__ Wt1, const float* __restrict__ b_t1,
    const unsigned short* __restrict__ Wt2, const float* __restrict__ b_t2,
    float* __restrict__ out)
{
    __shared__ __align__(16) unsigned short W1l[16384];   // Wt1 (32KB)
    __shared__ __align__(16) unsigned short W2l[16384];   // Wt2 (32KB)
    __shared__ __align__(16) unsigned short Wwl[4096];    // Wtw (8KB)

    const int tid  = threadIdx.x;
    const int lane = tid & 63;
    const int wv   = tid >> 6;           // 0..7
    const int l15  = lane & 15;
    const int lk   = lane >> 4;
    const int tile = (blockIdx.x * 8 + wv) * 32;
    const int swz7 = (l15 & 7) << 4;
    const int swz3 = (l15 & 3) << 4;

    // ---- stage ALL weights (one burst, swizzled writes; 512 thr) ----
    #pragma unroll
    for (int i = 0; i < 4; ++i) {
        const int c   = tid + i * 512;
        const int row = c >> 4, c16 = c & 15;
        const int off = (row * 256 + c16 * 16) ^ ((row & 7) << 4);
        *(uint4*)((char*)W1l + off) = *(const uint4*)&Wt1[row * 128 + c16 * 8];
        *(uint4*)((char*)W2l + off) = *(const uint4*)&Wt2[row * 128 + c16 * 8];
    }
    {
        const int c   = tid;             // 512 chunks, 1 iter
        const int row = c >> 2, c4 = c & 3;
        uint4 v = *(const uint4*)&Wtw[row * 32 + c4 * 8];
        *(uint4*)((char*)Wwl + ((row * 64 + c4 * 16) ^ ((row & 3) << 4))) = v;
    }

    // ---- B-frags: t_ij edges direct from global (lane l15 = edge col) ----
    bf16x8 a1[4][2];
    #pragma unroll
    for (int kt = 0; kt < 4; ++kt)
        #pragma unroll
        for (int rt = 0; rt < 2; ++rt) {
            const float* p = t_ij + (size_t)(tile + rt * 16 + l15) * 128
                           + kt * 32 + lk * 8;
            a1[kt][rt] = pack8(*(const float4*)p, *(const float4*)(p + 4));
        }

    // ---- wn B-frags (lane l15 = edge col, k = r = lk*8..+7) ----
    bf16x8 wnf[2];
    #pragma unroll
    for (int rt = 0; rt < 2; ++rt)
        wnf[rt] = *(const bf16x8*)&wn[(size_t)(tile + rt * 16 + l15) * 32 + lk * 8];

    __syncthreads();   // the ONLY barrier

    // ---- GEMM1: h = silu(t @ W_t1 + b_t1), kept in registers ----
    bf16x4 h[2][8];    // [rt][ct1]: lane l15 = edge, elems = n (k for GEMM2)
    #pragma unroll
    for (int ct = 0; ct < 8; ++ct) {
        bf16x8 w1f[4];
        #pragma unroll
        for (int kt = 0; kt < 4; ++kt)
            w1f[kt] = *(const bf16x8*)((const char*)W1l +
                (((ct * 16 + l15) * 256 + kt * 64 + lk * 16) ^ swz7));
        f32x4 ac[2];
        #pragma unroll
        for (int rt = 0; rt < 2; ++rt) ac[rt] = (f32x4){0.f, 0.f, 0.f, 0.f};
        #pragma unroll
        for (int kt = 0; kt < 4; ++kt)
            #pragma unroll
            for (int rt = 0; rt < 2; ++rt)
                ac[rt] = mfma16(w1f[kt], a1[kt][rt], ac[rt]);

        const float4 bt1 = *(const float4*)&b_t1[ct * 16 + lk * 4];
        #pragma unroll
        for (int rt = 0; rt < 2; ++rt)
            h[rt][ct] = pack4(silu_f(ac[rt][0] + bt1.x),
                              silu_f(ac[rt][1] + bt1.y),
                              silu_f(ac[rt][2] + bt1.z),
                              silu_f(ac[rt][3] + bt1.w));
    }

    // ---- GEMM2 + dw + epilogue, SWAPPED operands -> D[n][edge] ----
    #pragma unroll
    for (int ct2 = 0; ct2 < 8; ++ct2) {
        bf16x4 w2b[8];      // A-frag: row n = ct2*16+l15, k = ct1*16+lk*4..+3
        #pragma unroll
        for (int ct1 = 0; ct1 < 8; ++ct1)
            w2b[ct1] = *(const bf16x4*)((const char*)W2l +
                (((ct2 * 16 + l15) * 256 + ct1 * 32 + lk * 8) ^ swz7));
        bf16x8 wwf = *(const bf16x8*)((const char*)Wwl +
            (((ct2 * 16 + l15) * 64 + lk * 16) ^ swz3));
        const float4 bwv = *(const float4*)&b_w[ct2 * 16 + lk * 4];
        const float4 b2v = *(const float4*)&b_t2[ct2 * 16 + lk * 4];

        #pragma unroll
        for (int rt = 0; rt < 2; ++rt) {
            f32x4 o = (f32x4){0.f, 0.f, 0.f, 0.f};
            #pragma unroll
            for (int ct1 = 0; ct1 < 8; ++ct1)
                o = mfma_k16(w2b[ct1], h[rt][ct1], o);      // A=W2, B=h
            f32x4 d = mfma16(wwf, wnf[rt], (f32x4){0.f, 0.f, 0.f, 0.f});

            // lane l15 = edge, j = consecutive n -> one float4 store
            float4 s;
            s.x = (d[0] + bwv.x) * silu_f(o[0] + b2v.x);
            s.y = (d[1] + bwv.y) * silu_f(o[1] + b2v.y);
            s.z = (d[2] + bwv.z) * silu_f(o[2] + b2v.z);
            s.w = (d[3] + bwv.w) * silu_f(o[3] + b2v.w);
            *(float4*)&out[(size_t)(tile + rt * 16 + l15) * 128
                           + ct2 * 16 + lk * 4] = s;
        }
    }
}

extern "C" void kernel_launch(void* const* d_in, const int* in_sizes, int n_in,
                              void* d_out, int out_size, void* d_ws, size_t ws_size,
                              hipStream_t stream) {
    (void)in_sizes; (void)n_in; (void)out_size; (void)ws_size;
    const float* X0   = (const float*)d_in[0];
    const float* X1   = (const float*)d_in[1];
    const float* X2   = (const float*)d_in[2];
    const float* t_ij = (const float*)d_in[3];
    const float* r0   = (const float*)d_in[4];
    const float* r1   = (const float*)d_in[5];
    const float* r2   = (const float*)d_in[6];
    const int*   eidx = (const int*)d_in[7];
    const float* Wvq  = (const float*)d_in[8];
    const float* Wvk0 = (const float*)d_in[9];
    const float* Wvk1 = (const float*)d_in[10];
    const float* Wvk2 = (const float*)d_in[11];
    const float* ln_g = (const float*)d_in[12];
    const float* ln_b = (const float*)d_in[13];
    const float* W_w  = (const float*)d_in[14];
    const float* b_w  = (const float*)d_in[15];
    const float* W_t1 = (const float*)d_in[16];
    const float* b_t1 = (const float*)d_in[17];
    const float* W_t2 = (const float*)d_in[18];
    const float* b_t2 = (const float*)d_in[19];
    float* out = (float*)d_out;

    unsigned short* eq   = (unsigned short*)d_ws;          // [N][16 l][32 r] bf16
    unsigned short* ek   = eq  + (size_t)N_NODES * 512;
    unsigned short* wn   = ek  + (size_t)N_NODES * 512;    // [E,32] bf16
    unsigned short* Wtw  = wn  + (size_t)N_EDGES * 32;
    unsigned short* Wt1b = Wtw  + 4096;
    unsigned short* Wt2b = Wt1b + 16384;
    unsigned short* Wqt  = Wt2b + 16384;
    unsigned short* Wk0t = Wqt  + 4096;
    unsigned short* Wk1t = Wk0t + 4096;
    unsigned short* Wk2t = Wk1t + 4096;

    prep_kernel<<<64, 256, 0, stream>>>(W_w, W_t1, W_t2, Wvq, Wvk0, Wvk1, Wvk2,
                                        Wtw, Wt1b, Wt2b, Wqt, Wk0t, Wk1t, Wk2t);
    proj_kernel<<<1920, 256, 0, stream>>>(X0, X1, X2, Wqt, Wk0t, Wk1t, Wk2t,
                                          eq, ek);
    wn_kernel<<<N_EDGES / 16, 256, 0, stream>>>(eq, ek, r0, r1, r2, eidx,
                                                ln_g, ln_b, wn);
    edge_kernel<<<N_EDGES / 256, 512, 0, stream>>>(t_ij, wn, Wtw, b_w,
                                                   Wt1b, b_t1, Wt2b, b_t2, out);
}

// Round 19
// 94.417 us; speedup vs baseline: 1.0680x; 1.0680x over previous
//
#include <hip/hip_runtime.h>
#include <hip/hip_bf16.h>

#define N_NODES 8192
#define N_EDGES 131072
#define LN_EPS  1e-5f

typedef __attribute__((ext_vector_type(8))) short bf16x8;
typedef __attribute__((ext_vector_type(4))) short bf16x4;
typedef __attribute__((ext_vector_type(4))) float f32x4;

// silu via v_rcp_f32: avoids IEEE div expansion (no fast-math in harness)
__device__ __forceinline__ float silu_f(float x) {
    return x * __builtin_amdgcn_rcpf(1.0f + __expf(-x));
}

// fp32 -> bf16 RNE (scalar)
__device__ __forceinline__ unsigned short f2bf(float x) {
    union { float f; unsigned int u; } v; v.f = x;
    unsigned int r = v.u + 0x7FFFu + ((v.u >> 16) & 1u);
    return (unsigned short)(r >> 16);
}
__device__ __forceinline__ float bf2f(unsigned short u) {
    union { float f; unsigned int x; } v; v.x = ((unsigned int)u) << 16;
    return v.f;
}
// fp32 pair -> packed bf16x2 via v_cvt_pk_bf16_f32
__device__ __forceinline__ unsigned int pk2(float a, float b) {
    float2 t; t.x = a; t.y = b;
    union { __hip_bfloat162 h; unsigned int u; } v;
    v.h = __float22bfloat162_rn(t);
    return v.u;
}
__device__ __forceinline__ bf16x8 pack8(float4 u, float4 v) {
    union { bf16x8 b; unsigned int w[4]; } o;
    o.w[0] = pk2(u.x, u.y); o.w[1] = pk2(u.z, u.w);
    o.w[2] = pk2(v.x, v.y); o.w[3] = pk2(v.z, v.w);
    return o.b;
}
__device__ __forceinline__ bf16x4 pack4(float a, float b, float c, float d) {
    union { bf16x4 v; unsigned int u[2]; } o;
    o.u[0] = pk2(a, b); o.u[1] = pk2(c, d);
    return o.v;
}
__device__ __forceinline__ f32x4 mfma16(bf16x8 a, bf16x8 b, f32x4 c) {
    return __builtin_amdgcn_mfma_f32_16x16x32_bf16(a, b, c, 0, 0, 0);
}
// K=16 MFMA: A/B = 4 bf16 per lane (lane l15 = row/col, k = lk*4..+3)
#if __has_builtin(__builtin_amdgcn_mfma_f32_16x16x16bf16_1k)
__device__ __forceinline__ f32x4 mfma_k16(bf16x4 a, bf16x4 b, f32x4 c) {
    return __builtin_amdgcn_mfma_f32_16x16x16bf16_1k(a, b, c, 0, 0, 0);
}
#else
__device__ __forceinline__ f32x4 mfma_k16(bf16x4 a, bf16x4 b, f32x4 c) {
    f32x4 d;
    asm("v_mfma_f32_16x16x16_bf16 %0, %1, %2, %3"
        : "=v"(d) : "v"(a), "v"(b), "v"(c));
    return d;
}
#endif

// ---------------------------------------------------------------------------
// Kernel 0: weight prep (verified, unchanged).
// ---------------------------------------------------------------------------
__global__ __launch_bounds__(256) void prep_kernel(
    const float* __restrict__ W_w, const float* __restrict__ W_t1,
    const float* __restrict__ W_t2, const float* __restrict__ Wvq,
    const float* __restrict__ Wvk0, const float* __restrict__ Wvk1,
    const float* __restrict__ Wvk2,
    unsigned short* __restrict__ Wtw, unsigned short* __restrict__ Wt1b,
    unsigned short* __restrict__ Wt2b, unsigned short* __restrict__ Wqt,
    unsigned short* __restrict__ Wk0t, unsigned short* __restrict__ Wk1t,
    unsigned short* __restrict__ Wk2t)
{
    int i = blockIdx.x * 256 + threadIdx.x;
    if (i < 16384) {
        int n = i >> 7, k = i & 127;
        Wt1b[i] = f2bf(W_t1[k * 128 + n]);
        Wt2b[i] = f2bf(W_t2[k * 128 + n]);
    }
    if (i < 4096) {
        { int n = i >> 5, k = i & 31; Wtw[i] = f2bf(W_w[k * 128 + n]); }
        int r = i >> 7, d = i & 127;
        Wqt[i]  = f2bf(Wvq [d * 32 + r]);
        Wk0t[i] = f2bf(Wvk0[d * 32 + r]);
        Wk1t[i] = f2bf(Wvk1[d * 32 + r]);
        Wk2t[i] = f2bf(Wvk2[d * 32 + r]);
    }
}

// ---------------------------------------------------------------------------
// Kernel 1: MFMA projections (round-12 verified, unchanged). [n][l][r32].
// ---------------------------------------------------------------------------
template<int S, int LOFF>
__device__ __forceinline__ void proj_body(
    const float* __restrict__ X, const unsigned short* __restrict__ Wqt,
    const unsigned short* __restrict__ Wkt,
    unsigned short* __restrict__ eq, unsigned short* __restrict__ ek,
    int row0)
{
    const int tid  = threadIdx.x;
    const int lane = tid & 63;
    const int wv   = tid >> 6;
    const int l15  = lane & 15;
    const int lk   = lane >> 4;
    const int xrow = row0 + wv * 16 + l15;

    bf16x8 xf[4];
    #pragma unroll
    for (int kt = 0; kt < 4; ++kt) {
        const float* p = X + (size_t)xrow * 128 + kt * 32 + lk * 8;
        xf[kt] = pack8(*(const float4*)p, *(const float4*)(p + 4));
    }

    f32x4 qa[2], ka[2];
    #pragma unroll
    for (int h = 0; h < 2; ++h) {
        qa[h] = (f32x4){0.f, 0.f, 0.f, 0.f};
        ka[h] = (f32x4){0.f, 0.f, 0.f, 0.f};
    }
    #pragma unroll
    for (int kt = 0; kt < 4; ++kt) {
        #pragma unroll
        for (int h = 0; h < 2; ++h) {
            bf16x8 wq = *(const bf16x8*)&Wqt[(h * 16 + l15) * 128 + kt * 32 + lk * 8];
            bf16x8 wk = *(const bf16x8*)&Wkt[(h * 16 + l15) * 128 + kt * 32 + lk * 8];
            qa[h] = mfma16(wq, xf[kt], qa[h]);
            ka[h] = mfma16(wk, xf[kt], ka[h]);
        }
    }

    const int n = xrow / S;
    const int l = xrow % S + LOFF;
    const size_t base = (size_t)n * 512 + (size_t)l * 32;   // [n][l][r32]
    #pragma unroll
    for (int h = 0; h < 2; ++h) {
        union { ushort4 s; unsigned int u[2]; } pq, pk_;
        pq.u[0]  = pk2(qa[h][0], qa[h][1]); pq.u[1]  = pk2(qa[h][2], qa[h][3]);
        pk_.u[0] = pk2(ka[h][0], ka[h][1]); pk_.u[1] = pk2(ka[h][2], ka[h][3]);
        *(ushort4*)&eq[base + h * 16 + lk * 4] = pq.s;
        *(ushort4*)&ek[base + h * 16 + lk * 4] = pk_.s;
    }
}

__global__ __launch_bounds__(256) void proj_kernel(
    const float* __restrict__ X0, const float* __restrict__ X1,
    const float* __restrict__ X2,
    const unsigned short* __restrict__ Wqt,
    const unsigned short* __restrict__ Wk0t,
    const unsigned short* __restrict__ Wk1t,
    const unsigned short* __restrict__ Wk2t,
    unsigned short* __restrict__ eq, unsigned short* __restrict__ ek)
{
    const int b = blockIdx.x;
    if (b < 384)
        proj_body<3, 0>(X0, Wqt, Wk0t, eq, ek, b * 64);
    else if (b < 1024)
        proj_body<5, 3>(X1, Wqt, Wk1t, eq, ek, (b - 384) * 64);
    else
        proj_body<7, 8>(X2, Wqt, Wk2t, eq, ek, (b - 1024) * 64);
}

// ---------------------------------------------------------------------------
// Kernel 2: wn (round-12 verified, unchanged). 2 edges/thread, [n][l][r32].
// ---------------------------------------------------------------------------
__device__ __forceinline__ float edge_w_f(
    const float* qv, const float* kv, const float* rv)
{
    float qk = 0.f;
    #pragma unroll
    for (int l = 0; l < 15; ++l) qk = fmaf(qv[l], kv[l], qk);
    float c0 = 2.f, c1 = 2.f, c2 = 2.f;
    #pragma unroll
    for (int l = 0; l < 3; ++l)  c0 -= rv[l] * rv[l];
    #pragma unroll
    for (int l = 3; l < 8; ++l)  c1 -= rv[l] * rv[l];
    #pragma unroll
    for (int l = 8; l < 15; ++l) c2 -= rv[l] * rv[l];
    float dq0 = 0.f, dk0 = 0.f, dq1 = 0.f, dk1 = 0.f, dq2 = 0.f, dk2 = 0.f;
    #pragma unroll
    for (int l = 0; l < 3; ++l)  { dq0 = fmaf(qv[l], rv[l], dq0); dk0 = fmaf(kv[l], rv[l], dk0); }
    #pragma unroll
    for (int l = 3; l < 8; ++l)  { dq1 = fmaf(qv[l], rv[l], dq1); dk1 = fmaf(kv[l], rv[l], dk1); }
    #pragma unroll
    for (int l = 8; l < 15; ++l) { dq2 = fmaf(qv[l], rv[l], dq2); dk2 = fmaf(kv[l], rv[l], dk2); }
    return qk - dq0 * dk0 * c0 - dq1 * dk1 * c1 - dq2 * dk2 * c2;
}

__global__ __launch_bounds__(256) void wn_kernel(
    const unsigned short* __restrict__ eq, const unsigned short* __restrict__ ek,
    const float* __restrict__ r0, const float* __restrict__ r1,
    const float* __restrict__ r2, const int* __restrict__ eidx,
    const float* __restrict__ ln_g, const float* __restrict__ ln_b,
    unsigned short* __restrict__ wn)
{
    const int tid = threadIdx.x;
    const int r   = tid & 31;
    const int hw  = tid >> 5;
    const int e0  = blockIdx.x * 16 + hw * 2;
    const int e1  = e0 + 1;
    const float g  = ln_g[r];
    const float bb = ln_b[r];

    const int nj0 = eidx[e0], ni0 = eidx[N_EDGES + e0];
    const int nj1 = eidx[e1], ni1 = eidx[N_EDGES + e1];

    const unsigned short* qp0 = eq + (size_t)ni0 * 512 + r;
    const unsigned short* kp0 = ek + (size_t)nj0 * 512 + r;
    const unsigned short* qp1 = eq + (size_t)ni1 * 512 + r;
    const unsigned short* kp1 = ek + (size_t)nj1 * 512 + r;

    float qv0[15], kv0[15], qv1[15], kv1[15];
    #pragma unroll
    for (int l = 0; l < 15; ++l) {
        qv0[l] = bf2f(qp0[l * 32]);
        kv0[l] = bf2f(kp0[l * 32]);
        qv1[l] = bf2f(qp1[l * 32]);
        kv1[l] = bf2f(kp1[l * 32]);
    }

    float rva[15], rvb[15];
    #pragma unroll
    for (int c = 0; c < 3; ++c) { rva[c]     = r0[e0 * 3 + c]; rvb[c]     = r0[e1 * 3 + c]; }
    #pragma unroll
    for (int c = 0; c < 5; ++c) { rva[3 + c] = r1[e0 * 5 + c]; rvb[3 + c] = r1[e1 * 5 + c]; }
    #pragma unroll
    for (int c = 0; c < 7; ++c) { rva[8 + c] = r2[e0 * 7 + c]; rvb[8 + c] = r2[e1 * 7 + c]; }

    const float w0 = edge_w_f(qv0, kv0, rva);
    const float w1 = edge_w_f(qv1, kv1, rvb);

    float s0 = w0, s20 = w0 * w0, s1 = w1, s21 = w1 * w1;
    #pragma unroll
    for (int off = 1; off < 32; off <<= 1) {
        s0  += __shfl_xor(s0,  off); s20 += __shfl_xor(s20, off);
        s1  += __shfl_xor(s1,  off); s21 += __shfl_xor(s21, off);
    }
    const float mu0   = s0 * (1.f / 32.f);
    const float var0  = s20 * (1.f / 32.f) - mu0 * mu0;
    const float mu1   = s1 * (1.f / 32.f);
    const float var1  = s21 * (1.f / 32.f) - mu1 * mu1;
    wn[(size_t)e0 * 32 + r] = f2bf((w0 - mu0) * rsqrtf(var0 + LN_EPS) * g + bb);
    wn[(size_t)e1 * 32 + r] = f2bf((w1 - mu1) * rsqrtf(var1 + LN_EPS) * g + bb);
}

// ---------------------------------------------------------------------------
// Kernel 3: SINGLE-STAGE LDS-weight MFMA pipeline (round-14 verified best).
// 512 threads = 8 waves x 32 edges = 256 edges/block, grid 512.
// LDS 72KB -> 2 blocks/CU -> 16 waves/CU (4/SIMD). One barrier.
// ---------------------------------------------------------------------------
__global__ __launch_bounds__(512, 4) void edge_kernel(
    const float* __restrict__ t_ij,
    const unsigned short* __restrict__ wn,
    const unsigned short* __restrict__ Wtw, const float* __restrict__ b_w,
    const unsigned short* __restrict__ Wt1, const float* __restrict__ b_t1,
    const unsigned short* __restrict__ Wt2, const float* __restrict__ b_t2,
    float* __restrict__ out)
{
    __shared__ __align__(16) unsigned short W1l[16384];   // Wt1 (32KB)
    __shared__ __align__(16) unsigned short W2l[16384];   // Wt2 (32KB)
    __shared__ __align__(16) unsigned short Wwl[4096];    // Wtw (8KB)

    const int tid  = threadIdx.x;
    const int lane = tid & 63;
    const int wv   = tid >> 6;           // 0..7
    const int l15  = lane & 15;
    const int lk   = lane >> 4;
    const int tile = (blockIdx.x * 8 + wv) * 32;
    const int swz7 = (l15 & 7) << 4;
    const int swz3 = (l15 & 3) << 4;

    // ---- stage ALL weights (one burst, swizzled writes; 512 thr) ----
    #pragma unroll
    for (int i = 0; i < 4; ++i) {
        const int c   = tid + i * 512;
        const int row = c >> 4, c16 = c & 15;
        const int off = (row * 256 + c16 * 16) ^ ((row & 7) << 4);
        *(uint4*)((char*)W1l + off) = *(const uint4*)&Wt1[row * 128 + c16 * 8];
        *(uint4*)((char*)W2l + off) = *(const uint4*)&Wt2[row * 128 + c16 * 8];
    }
    {
        const int c   = tid;             // 512 chunks, 1 iter
        const int row = c >> 2, c4 = c & 3;
        uint4 v = *(const uint4*)&Wtw[row * 32 + c4 * 8];
        *(uint4*)((char*)Wwl + ((row * 64 + c4 * 16) ^ ((row & 3) << 4))) = v;
    }

    // ---- B-frags: t_ij edges direct from global (lane l15 = edge col) ----
    bf16x8 a1[4][2];
    #pragma unroll
    for (int kt = 0; kt < 4; ++kt)
        #pragma unroll
        for (int rt = 0; rt < 2; ++rt) {
            const float* p = t_ij + (size_t)(tile + rt * 16 + l15) * 128
                           + kt * 32 + lk * 8;
            a1[kt][rt] = pack8(*(const float4*)p, *(const float4*)(p + 4));
        }

    // ---- wn A-frags (lane l15 = edge row, k = r = lk*8..+7) ----
    bf16x8 wnf[2];
    #pragma unroll
    for (int rt = 0; rt < 2; ++rt)
        wnf[rt] = *(const bf16x8*)&wn[(size_t)(tile + rt * 16 + l15) * 32 + lk * 8];

    __syncthreads();   // the ONLY barrier

    // ---- GEMM1: h = silu(t @ W_t1 + b_t1), kept in registers ----
    bf16x4 h[2][8];    // [rt][ct1]: lane's mfma_k16 A-frag (row = edge l15)
    #pragma unroll
    for (int ct = 0; ct < 8; ++ct) {
        bf16x8 w1f[4];
        #pragma unroll
        for (int kt = 0; kt < 4; ++kt)
            w1f[kt] = *(const bf16x8*)((const char*)W1l +
                (((ct * 16 + l15) * 256 + kt * 64 + lk * 16) ^ swz7));
        f32x4 ac[2];
        #pragma unroll
        for (int rt = 0; rt < 2; ++rt) ac[rt] = (f32x4){0.f, 0.f, 0.f, 0.f};
        #pragma unroll
        for (int kt = 0; kt < 4; ++kt)
            #pragma unroll
            for (int rt = 0; rt < 2; ++rt)
                ac[rt] = mfma16(w1f[kt], a1[kt][rt], ac[rt]);

        const float4 bt1 = *(const float4*)&b_t1[ct * 16 + lk * 4];
        #pragma unroll
        for (int rt = 0; rt < 2; ++rt)
            h[rt][ct] = pack4(silu_f(ac[rt][0] + bt1.x),
                              silu_f(ac[rt][1] + bt1.y),
                              silu_f(ac[rt][2] + bt1.z),
                              silu_f(ac[rt][3] + bt1.w));
    }

    // ---- GEMM2 + dw + epilogue (no barrier needed; W2l/Wwl resident) ----
    #pragma unroll
    for (int ct2 = 0; ct2 < 8; ++ct2) {
        bf16x4 w2b[8];
        #pragma unroll
        for (int ct1 = 0; ct1 < 8; ++ct1)
            w2b[ct1] = *(const bf16x4*)((const char*)W2l +
                (((ct2 * 16 + l15) * 256 + ct1 * 32 + lk * 8) ^ swz7));
        bf16x8 wwf = *(const bf16x8*)((const char*)Wwl +
            (((ct2 * 16 + l15) * 64 + lk * 16) ^ swz3));
        const float bwv = b_w[ct2 * 16 + l15];
        const float b2v = b_t2[ct2 * 16 + l15];

        #pragma unroll
        for (int rt = 0; rt < 2; ++rt) {
            f32x4 o = (f32x4){0.f, 0.f, 0.f, 0.f};
            #pragma unroll
            for (int ct1 = 0; ct1 < 8; ++ct1)
                o = mfma_k16(h[rt][ct1], w2b[ct1], o);
            f32x4 d = mfma16(wnf[rt], wwf, (f32x4){0.f, 0.f, 0.f, 0.f});

            float* op = out + (size_t)(tile + rt * 16 + lk * 4) * 128
                      + ct2 * 16 + l15;
            #pragma unroll
            for (int j = 0; j < 4; ++j)
                op[j * 128] = (d[j] + bwv) * silu_f(o[j] + b2v);
        }
    }
}

extern "C" void kernel_launch(void* const* d_in, const int* in_sizes, int n_in,
                              void* d_out, int out_size, void* d_ws, size_t ws_size,
                              hipStream_t stream) {
    (void)in_sizes; (void)n_in; (void)out_size; (void)ws_size;
    const float* X0   = (const float*)d_in[0];
    const float* X1   = (const float*)d_in[1];
    const float* X2   = (const float*)d_in[2];
    const float* t_ij = (const float*)d_in[3];
    const float* r0   = (const float*)d_in[4];
    const float* r1   = (const float*)d_in[5];
    const float* r2   = (const float*)d_in[6];
    const int*   eidx = (const int*)d_in[7];
    const float* Wvq  = (const float*)d_in[8];
    const float* Wvk0 = (const float*)d_in[9];
    const float* Wvk1 = (const float*)d_in[10];
    const float* Wvk2 = (const float*)d_in[11];
    const float* ln_g = (const float*)d_in[12];
    const float* ln_b = (const float*)d_in[13];
    const float* W_w  = (const float*)d_in[14];
    const float* b_w  = (const float*)d_in[15];
    const float* W_t1 = (const float*)d_in[16];
    const float* b_t1 = (const float*)d_in[17];
    const float* W_t2 = (const float*)d_in[18];
    const float* b_t2 = (const float*)d_in[19];
    float* out = (float*)d_out;

    unsigned short* eq   = (unsigned short*)d_ws;          // [N][16 l][32 r] bf16
    unsigned short* ek   = eq  + (size_t)N_NODES * 512;
    unsigned short* wn   = ek  + (size_t)N_NODES * 512;    // [E,32] bf16
    unsigned short* Wtw  = wn  + (size_t)N_EDGES * 32;
    unsigned short* Wt1b = Wtw  + 4096;
    unsigned short* Wt2b = Wt1b + 16384;
    unsigned short* Wqt  = Wt2b + 16384;
    unsigned short* Wk0t = Wqt  + 4096;
    unsigned short* Wk1t = Wk0t + 4096;
    unsigned short* Wk2t = Wk1t + 4096;

    prep_kernel<<<64, 256, 0, stream>>>(W_w, W_t1, W_t2, Wvq, Wvk0, Wvk1, Wvk2,
                                        Wtw, Wt1b, Wt2b, Wqt, Wk0t, Wk1t, Wk2t);
    proj_kernel<<<1920, 256, 0, stream>>>(X0, X1, X2, Wqt, Wk0t, Wk1t, Wk2t,
                                          eq, ek);
    wn_kernel<<<N_EDGES / 16, 256, 0, stream>>>(eq, ek, r0, r1, r2, eidx,
                                                ln_g, ln_b, wn);
    edge_kernel<<<N_EDGES / 256, 512, 0, stream>>>(t_ij, wn, Wtw, b_w,
                                                   Wt1b, b_t1, Wt2b, b_t2, out);
}